// Round 18
// baseline (120.855 us; speedup 1.0000x reference)
//
#include <hip/hip_runtime.h>

#define IN_F 1024
#define OUT_F 1024
#define NNZ 16384

typedef _Float16 f16;
typedef _Float16 f16x8 __attribute__((ext_vector_type(8)));
typedef float f32x4 __attribute__((ext_vector_type(4)));
typedef unsigned short ushort8 __attribute__((ext_vector_type(8)));

#define AS1 __attribute__((address_space(1)))
#define AS3 __attribute__((address_space(3)))

// ---------------------------------------------------------------------------
// Best-measured assembly (r18):
//   prep_base (linear W cvt) -> conv_x v6 (linear X cvt + fused scatter)
//   -> gemm12 (256-tile, single-barrier, triple-A, schedule-free; ~71 us,
//   MfmaUtil ~37%, 0 bank conflicts, replay-proven r15/r16).
// Session ledger: schedule x7, MFMA shape, B-placement, LDS size/occupancy
// all measured; gemm12 is the plain-HIP optimum found (~980 TF).
//
// Workspace: Wl = LINEAR W_eff (f16, 2 MiB) @0; Xs (LINEAR f16 X) @2MiB+4096.
// Swizzle lives in the DMA source address (m173); LDS dest linear; ds_read
// applies the same XOR (G21 both-sides).
// SYNC INVARIANT (r9): DMA-staged LDS is written by ALL waves; vmcnt drains
// only the issuing wave's loads -> VMW(n) -> s_barrier before cross-wave read.
// ---------------------------------------------------------------------------

__device__ __forceinline__ int compute_mode(const unsigned short* __restrict__ w,
                                            float* smax, int* semax) {
  int t = threadIdx.x;
  const float* wf = (const float*)w;
  float m32 = fmaxf(fabsf(wf[t]), fabsf(wf[t + 256]));
  int e8 = 0;
#pragma unroll
  for (int j = 0; j < 8; ++j) {
    unsigned short u = w[t * 8 + j];
    int e = (u >> 7) & 0xFF;
    e8 = e > e8 ? e : e8;
  }
  smax[t] = m32; semax[t] = e8;
  __syncthreads();
  for (int s = 128; s > 0; s >>= 1) {
    if (t < s) {
      smax[t] = fmaxf(smax[t], smax[t + s]);
      semax[t] = semax[t] > semax[t + s] ? semax[t] : semax[t + s];
    }
    __syncthreads();
  }
  int m;
  if (!(smax[0] > 1e-6f)) m = 2;        // native f16
  else if (semax[0] >= 140) m = 0;      // f32-upcast
  else m = 1;                           // bf16
  return m;
}

__device__ __forceinline__ float load_w(const void* base, size_t i, int mode) {
  if (mode == 0) return ((const float*)base)[i];
  if (mode == 1) {
    unsigned int u = (unsigned int)((const unsigned short*)base)[i] << 16;
    return __uint_as_float(u);
  }
  return (float)((const f16*)base)[i];
}

__global__ void prep_base(const void* __restrict__ base, f16* __restrict__ Wl) {
  __shared__ float smax[256];
  __shared__ int semax[256];
  int mode = compute_mode((const unsigned short*)base, smax, semax);
  int id = blockIdx.x * 256 + threadIdx.x;
  size_t off = (size_t)id * 8;
  f16x8 h;
  if (mode == 0) {
    const float* b = (const float*)base + off;
    float4 v0 = *reinterpret_cast<const float4*>(b);
    float4 v1 = *reinterpret_cast<const float4*>(b + 4);
    h = (f16x8){(f16)v0.x, (f16)v0.y, (f16)v0.z, (f16)v0.w,
                (f16)v1.x, (f16)v1.y, (f16)v1.z, (f16)v1.w};
  } else if (mode == 1) {
    ushort8 uv = *reinterpret_cast<const ushort8*>((const unsigned short*)base + off);
#pragma unroll
    for (int j = 0; j < 8; ++j)
      h[j] = (f16)__uint_as_float((unsigned int)uv[j] << 16);
  } else {
    h = *reinterpret_cast<const f16x8*>((const f16*)base + off);
  }
  *reinterpret_cast<f16x8*>(Wl + off) = h;
}

// conv_x v6: linear cvt copy + fused scatter (blocks < 64; NNZ = 64*256).
// Runs after prep_base on the stream, so the scatter's WAW on Wl is ordered.
__global__ void __launch_bounds__(256) conv_x(const float* __restrict__ X,
                                              f16* __restrict__ Xs, int total,
                                              const void* __restrict__ base,
                                              const void* __restrict__ vals,
                                              const int* __restrict__ idx,
                                              const float* __restrict__ alpha,
                                              f16* __restrict__ Wl) {
  __shared__ float smax[256];
  __shared__ int semax[256];
  if (blockIdx.x < 64) {
    int mode = compute_mode((const unsigned short*)base, smax, semax);
    int i = blockIdx.x * 256 + threadIdx.x;   // i < 16384 = NNZ
    int id = idx[i];
    float v = load_w(base, id, mode) + alpha[0] * load_w(vals, i, mode);
    Wl[id] = (f16)v;
  }
  int stride = gridDim.x * 256;
  for (int id = blockIdx.x * 256 + threadIdx.x; id < total; id += stride) {
    size_t off = (size_t)id * 8;
    const float* p = X + off;
    float4 v0 = *reinterpret_cast<const float4*>(p);
    float4 v1 = *reinterpret_cast<const float4*>(p + 4);
    f16x8 h = {(f16)v0.x, (f16)v0.y, (f16)v0.z, (f16)v0.w,
               (f16)v1.x, (f16)v1.y, (f16)v1.z, (f16)v1.w};
    *reinterpret_cast<f16x8*>(Xs + off) = h;
  }
}

#define SB0 __builtin_amdgcn_sched_barrier(0)
#define VMW(N) asm volatile("s_waitcnt vmcnt(" #N ")" ::: "memory")

// ---------------------------------------------------------------------------
// gemm12 (replay-proven r15/r16): 256x256, BK=64, 512 thr (8 waves 2Mx4N),
// wave tile 128x64. LDS 160 KiB: A triple-buffered (3x32 KiB), B double
// (2x32 KiB). Tile body schedule-free (compiler emits counted lgkmcnt):
// {ds_read S0; issue QB(KT+1)->B[(KT+1)&1]; 32 MFMA; ds_read S1;
//  issue QA(KT+2)->A[(KT+2)%3]; 32 MFMA} -> VMW(4) (drains A/B(KT+1),
// keeps QA(KT+2)) -> s_barrier (WAR+RAW, r9) -> SB0 hoist guard.
// VMW(0) only prologue / KT=14.
// ---------------------------------------------------------------------------

#define ISSUE_QA11(QI, KT1, AP)                                                \
    __builtin_amdgcn_global_load_lds(                                          \
        (const AS1 void*)(Xs + rowOffA[QI] + (KT1) * 64 + swzc),               \
        (AS3 void*)(&sA[((AP) * 4 + (QI)) * 4096 + t * 8]), 16, 0, 0)

#define ISSUE_QB11(QI, KT1, BP)                                                \
    __builtin_amdgcn_global_load_lds(                                          \
        (const AS1 void*)(Wl + rowOffB[QI] + (KT1) * 64 + swzc),               \
        (AS3 void*)(&sB[((BP) * 4 + (QI)) * 4096 + t * 8]), 16, 0, 0)

#define DSREAD11(AP, BP, S_) do {                                              \
    _Pragma("unroll")                                                          \
    for (int qq_ = 0; qq_ < 2; ++qq_) {                                        \
      int qa_ = ((AP) * 4 + wm * 2 + qq_) * 4096;                              \
      _Pragma("unroll")                                                        \
      for (int mf_ = 0; mf_ < 4; ++mf_) {                                      \
        int r_ = mf_ * 16 + lr;                                                \
        int blk_ = ((S_) * 4 + lk) ^ (lr & 7);                                 \
        afr[qq_][mf_] = *reinterpret_cast<const f16x8*>(&sA[qa_ + r_ * 64 + blk_ * 8]); \
      }                                                                        \
    }                                                                          \
    int qb_ = ((BP) * 4 + wn) * 4096;                                          \
    _Pragma("unroll")                                                          \
    for (int nf_ = 0; nf_ < 4; ++nf_) {                                        \
      int r_ = nf_ * 16 + lr;                                                  \
      int blk_ = ((S_) * 4 + lk) ^ (lr & 7);                                   \
      bfr[nf_] = *reinterpret_cast<const f16x8*>(&sB[qb_ + r_ * 64 + blk_ * 8]); \
    }                                                                          \
  } while (0)

#define MFMA32_FREE do {                                                       \
    __builtin_amdgcn_s_setprio(1);                                             \
    _Pragma("unroll")                                                          \
    for (int qq_ = 0; qq_ < 2; ++qq_)                                          \
      _Pragma("unroll")                                                        \
      for (int mf_ = 0; mf_ < 4; ++mf_)                                        \
        _Pragma("unroll")                                                      \
        for (int nf_ = 0; nf_ < 4; ++nf_)                                      \
          acc[qq_ * 4 + mf_][nf_] = __builtin_amdgcn_mfma_f32_16x16x32_f16(    \
              afr[qq_][mf_], bfr[nf_], acc[qq_ * 4 + mf_][nf_], 0, 0, 0);      \
    __builtin_amdgcn_s_setprio(0);                                             \
  } while (0)

#define KTILE12(AP, BP, KT, ISSB, ISSA, VMN, LASTBAR) do {                     \
    DSREAD11(AP, BP, 0);                                                       \
    if (ISSB) {                                                                \
      ISSUE_QB11(0, (KT) + 1, ((KT) + 1) & 1); ISSUE_QB11(1, (KT) + 1, ((KT) + 1) & 1); \
      ISSUE_QB11(2, (KT) + 1, ((KT) + 1) & 1); ISSUE_QB11(3, (KT) + 1, ((KT) + 1) & 1); } \
    MFMA32_FREE;                                                               \
    DSREAD11(AP, BP, 1);                                                       \
    if (ISSA) {                                                                \
      ISSUE_QA11(0, (KT) + 2, ((KT) + 2) % 3); ISSUE_QA11(1, (KT) + 2, ((KT) + 2) % 3); \
      ISSUE_QA11(2, (KT) + 2, ((KT) + 2) % 3); ISSUE_QA11(3, (KT) + 2, ((KT) + 2) % 3); } \
    MFMA32_FREE;                                                               \
    if (LASTBAR) {                                                             \
      VMW(VMN);                                                                \
      __builtin_amdgcn_s_barrier();  /* WAR(this) + RAW(next), r9 */           \
      SB0;                           /* hoist guard */                         \
    }                                                                          \
  } while (0)

__global__ void __launch_bounds__(512, 2) gemm12(const f16* __restrict__ Xs,
                                                 const f16* __restrict__ Wl,
                                                 float* __restrict__ C) {
  extern __shared__ f16 lds[];
  f16* sA = lds;              // 3 bufs x [4 quarters][4096] = 96 KiB
  f16* sB = lds + 49152;      // 2 bufs x [4 quarters][4096] = 64 KiB

  int bidx = blockIdx.x;
  int q = gridDim.x >> 3;
  int wg = (bidx & 7) * q + (bidx >> 3);
  int mt = wg >> 2, nt = wg & 3;

  int t = threadIdx.x;
  int lane = t & 63;
  int w = t >> 6;
  int wm = w >> 2;
  int wn = w & 3;
  int lr = lane & 15;
  int lk = lane >> 4;

  int rS = t >> 3;
  int swzc = (((t & 7) ^ (rS & 7)) << 3);
  size_t rowOffA[4], rowOffB[4];
#pragma unroll
  for (int qi = 0; qi < 4; ++qi) {
    rowOffA[qi] = (size_t)(mt * 256 + qi * 64 + rS) * IN_F;
    rowOffB[qi] = (size_t)(nt * 256 + qi * 64 + rS) * IN_F;
  }

  f16x8 afr[2][4], bfr[4];
  f32x4 acc[8][4];
#pragma unroll
  for (int i = 0; i < 8; ++i)
#pragma unroll
    for (int j = 0; j < 4; ++j)
      acc[i][j] = (f32x4){0.f, 0.f, 0.f, 0.f};

  // prologue: QA(0)->A0, QB(0)->B0, QA(1)->A1; VMW(4); barrier (r9).
  ISSUE_QA11(0, 0, 0); ISSUE_QA11(1, 0, 0); ISSUE_QA11(2, 0, 0); ISSUE_QA11(3, 0, 0);
  ISSUE_QB11(0, 0, 0); ISSUE_QB11(1, 0, 0); ISSUE_QB11(2, 0, 0); ISSUE_QB11(3, 0, 0);
  ISSUE_QA11(0, 1, 1); ISSUE_QA11(1, 1, 1); ISSUE_QA11(2, 1, 1); ISSUE_QA11(3, 1, 1);
  VMW(4);
  __builtin_amdgcn_s_barrier();
  SB0;

  KTILE12(0, 0,  0, true,  true,  4, true);
  KTILE12(1, 1,  1, true,  true,  4, true);
  KTILE12(2, 0,  2, true,  true,  4, true);
  KTILE12(0, 1,  3, true,  true,  4, true);
  KTILE12(1, 0,  4, true,  true,  4, true);
  KTILE12(2, 1,  5, true,  true,  4, true);
  KTILE12(0, 0,  6, true,  true,  4, true);
  KTILE12(1, 1,  7, true,  true,  4, true);
  KTILE12(2, 0,  8, true,  true,  4, true);
  KTILE12(0, 1,  9, true,  true,  4, true);
  KTILE12(1, 0, 10, true,  true,  4, true);
  KTILE12(2, 1, 11, true,  true,  4, true);
  KTILE12(0, 0, 12, true,  true,  4, true);
  KTILE12(1, 1, 13, true,  true,  4, true);
  KTILE12(2, 0, 14, true,  false, 0, true);
  KTILE12(0, 1, 15, false, false, 0, false);

  // epilogue: D layout col = lane&15, row = (lane>>4)*4 + reg
  float* Cw = C + (size_t)(mt * 256 + wm * 128 + lk * 4) * OUT_F + nt * 256 + wn * 64 + lr;
#pragma unroll
  for (int m = 0; m < 8; ++m) {
    int rowo = (m >> 2) * 64 + (m & 3) * 16;
#pragma unroll
    for (int nf = 0; nf < 4; ++nf)
#pragma unroll
      for (int g = 0; g < 4; ++g)
        Cw[(size_t)(rowo + g) * OUT_F + nf * 16] = acc[m][nf][g];
  }
}

// ---------------------------------------------------------------------------
// gemm13 fallback (replay-proven r17, ~78 us): 128-tile, 80 KiB LDS.
// ---------------------------------------------------------------------------

#define ISSUE_QA13(QI, KT1, AP) do {                                           \
    __builtin_amdgcn_global_load_lds(                                          \
        (const AS1 void*)(Xs + rowOffA2[QI][0] + (KT1) * 64 + swzc),           \
        (AS3 void*)(&sA[((AP) * 2 + (QI)) * 4096 + t * 8]), 16, 0, 0);         \
    __builtin_amdgcn_global_load_lds(                                          \
        (const AS1 void*)(Xs + rowOffA2[QI][1] + (KT1) * 64 + swzc),           \
        (AS3 void*)(&sA[((AP) * 2 + (QI)) * 4096 + t * 8 + 2048]), 16, 0, 0);  \
  } while (0)

#define ISSUE_QB13(QI, KT1, BP) do {                                           \
    __builtin_amdgcn_global_load_lds(                                          \
        (const AS1 void*)(Wl + rowOffB2[QI][0] + (KT1) * 64 + swzc),           \
        (AS3 void*)(&sB[((BP) * 2 + (QI)) * 4096 + t * 8]), 16, 0, 0);         \
    __builtin_amdgcn_global_load_lds(                                          \
        (const AS1 void*)(Wl + rowOffB2[QI][1] + (KT1) * 64 + swzc),           \
        (AS3 void*)(&sB[((BP) * 2 + (QI)) * 4096 + t * 8 + 2048]), 16, 0, 0);  \
  } while (0)

#define DSREAD13(AP, BP, S_) do {                                              \
    int qa_ = ((AP) * 2 + wm) * 4096;                                          \
    _Pragma("unroll")                                                          \
    for (int mf_ = 0; mf_ < 4; ++mf_) {                                        \
      int r_ = mf_ * 16 + lr;                                                  \
      int blk_ = ((S_) * 4 + lk) ^ (lr & 7);                                   \
      afr2[mf_] = *reinterpret_cast<const f16x8*>(&sA[qa_ + r_ * 64 + blk_ * 8]); \
    }                                                                          \
    int qb_ = ((BP) * 2 + wn) * 4096;                                          \
    _Pragma("unroll")                                                          \
    for (int nf_ = 0; nf_ < 4; ++nf_) {                                        \
      int r_ = nf_ * 16 + lr;                                                  \
      int blk_ = ((S_) * 4 + lk) ^ (lr & 7);                                   \
      bfr2[nf_] = *reinterpret_cast<const f16x8*>(&sB[qb_ + r_ * 64 + blk_ * 8]); \
    }                                                                          \
  } while (0)

#define MFMA16F do {                                                           \
    __builtin_amdgcn_s_setprio(1);                                             \
    _Pragma("unroll")                                                          \
    for (int mf_ = 0; mf_ < 4; ++mf_)                                          \
      _Pragma("unroll")                                                        \
      for (int nf_ = 0; nf_ < 4; ++nf_)                                        \
        acc2[mf_][nf_] = __builtin_amdgcn_mfma_f32_16x16x32_f16(               \
            afr2[mf_], bfr2[nf_], acc2[mf_][nf_], 0, 0, 0);                    \
    __builtin_amdgcn_s_setprio(0);                                             \
  } while (0)

#define KTILE13(AP, BP, KT, ISSB, ISSA, VMN, LASTBAR) do {                     \
    DSREAD13(AP, BP, 0);                                                       \
    if (ISSB) { ISSUE_QB13(0, (KT) + 1, ((KT) + 1) & 1);                       \
                ISSUE_QB13(1, (KT) + 1, ((KT) + 1) & 1); }                     \
    MFMA16F;                                                                   \
    DSREAD13(AP, BP, 1);                                                       \
    if (ISSA) { ISSUE_QA13(0, (KT) + 2, ((KT) + 2) % 3);                       \
                ISSUE_QA13(1, (KT) + 2, ((KT) + 2) % 3); }                     \
    MFMA16F;                                                                   \
    if (LASTBAR) {                                                             \
      VMW(VMN);                                                                \
      __builtin_amdgcn_s_barrier();                                            \
      SB0;                                                                     \
    }                                                                          \
  } while (0)

__global__ void __launch_bounds__(256, 2) gemm13(const f16* __restrict__ Xs,
                                                 const f16* __restrict__ Wl,
                                                 float* __restrict__ C) {
  extern __shared__ f16 lds[];
  f16* sA = lds;
  f16* sB = lds + 24576;

  int bidx = blockIdx.x;
  int q = gridDim.x >> 3;
  int wg = (bidx & 7) * q + (bidx >> 3);
  int mt = wg >> 3, nt = wg & 7;

  int t = threadIdx.x;
  int lane = t & 63;
  int w = t >> 6;
  int wm = w >> 1;
  int wn = w & 1;
  int lr = lane & 15;
  int lk = lane >> 4;

  int rS = t >> 3;
  int swzc = (((t & 7) ^ (rS & 7)) << 3);
  size_t rowOffA2[2][2], rowOffB2[2][2];
#pragma unroll
  for (int qi = 0; qi < 2; ++qi)
#pragma unroll
    for (int h = 0; h < 2; ++h) {
      rowOffA2[qi][h] = (size_t)(mt * 128 + qi * 64 + h * 32 + rS) * IN_F;
      rowOffB2[qi][h] = (size_t)(nt * 128 + qi * 64 + h * 32 + rS) * IN_F;
    }

  f16x8 afr2[4], bfr2[4];
  f32x4 acc2[4][4];
#pragma unroll
  for (int i = 0; i < 4; ++i)
#pragma unroll
    for (int j = 0; j < 4; ++j)
      acc2[i][j] = (f32x4){0.f, 0.f, 0.f, 0.f};

  ISSUE_QA13(0, 0, 0); ISSUE_QA13(1, 0, 0);
  ISSUE_QB13(0, 0, 0); ISSUE_QB13(1, 0, 0);
  ISSUE_QA13(0, 1, 1); ISSUE_QA13(1, 1, 1);
  VMW(4);
  __builtin_amdgcn_s_barrier();
  SB0;

  KTILE13(0, 0,  0, true,  true,  4, true);
  KTILE13(1, 1,  1, true,  true,  4, true);
  KTILE13(2, 0,  2, true,  true,  4, true);
  KTILE13(0, 1,  3, true,  true,  4, true);
  KTILE13(1, 0,  4, true,  true,  4, true);
  KTILE13(2, 1,  5, true,  true,  4, true);
  KTILE13(0, 0,  6, true,  true,  4, true);
  KTILE13(1, 1,  7, true,  true,  4, true);
  KTILE13(2, 0,  8, true,  true,  4, true);
  KTILE13(0, 1,  9, true,  true,  4, true);
  KTILE13(1, 0, 10, true,  true,  4, true);
  KTILE13(2, 1, 11, true,  true,  4, true);
  KTILE13(0, 0, 12, true,  true,  4, true);
  KTILE13(1, 1, 13, true,  true,  4, true);
  KTILE13(2, 0, 14, true,  false, 0, true);
  KTILE13(0, 1, 15, false, false, 0, false);

  float* Cw = C + (size_t)(mt * 128 + wm * 64 + lk * 4) * OUT_F + nt * 128 + wn * 64 + lr;
#pragma unroll
  for (int mf = 0; mf < 4; ++mf)
#pragma unroll
    for (int nf = 0; nf < 4; ++nf)
#pragma unroll
      for (int g = 0; g < 4; ++g)
        Cw[(size_t)(mf * 16 + g) * OUT_F + nf * 16] = acc2[mf][nf][g];
}

extern "C" void kernel_launch(void* const* d_in, const int* in_sizes, int n_in,
                              void* d_out, int out_size, void* d_ws, size_t ws_size,
                              hipStream_t stream) {
  const float* X = (const float*)d_in[0];
  const void* base = d_in[1];
  const void* vals = d_in[2];
  const int* idx = (const int*)d_in[3];
  const float* alpha = (const float*)d_in[4];
  float* out = (float*)d_out;
  f16* Wl = (f16*)d_ws;                                   // linear W_eff
  f16* Xs = (f16*)((char*)d_ws + 2 * 1024 * 1024 + 4096); // linear f16 X

  int M = in_sizes[0] / IN_F;              // 32768
  int total = (M * IN_F) / 8;              // 8-f16 chunks

  prep_base<<<dim3(512), dim3(256), 0, stream>>>(base, Wl);
  conv_x<<<dim3(2048), dim3(256), 0, stream>>>(X, Xs, total, base, vals, idx, alpha, Wl);

  hipError_t e = hipFuncSetAttribute(reinterpret_cast<const void*>(&gemm12),
                                     hipFuncAttributeMaxDynamicSharedMemorySize, 163840);
  if (e == hipSuccess) {
    gemm12<<<dim3((M / 256) * 4), dim3(512), 163840, stream>>>(Xs, Wl, out);
  } else {
    (void)hipFuncSetAttribute(reinterpret_cast<const void*>(&gemm13),
                              hipFuncAttributeMaxDynamicSharedMemorySize, 81920);
    gemm13<<<dim3((M / 128) * 8), dim3(256), 81920, stream>>>(Xs, Wl, out);
  }
}

// Round 20
// 105.195 us; speedup vs baseline: 1.1489x; 1.1489x over previous
//
#include <hip/hip_runtime.h>

#define IN_F 1024
#define OUT_F 1024
#define NNZ 16384

typedef _Float16 f16;
typedef _Float16 f16x8 __attribute__((ext_vector_type(8)));
typedef float f32x4 __attribute__((ext_vector_type(4)));
typedef unsigned short ushort8 __attribute__((ext_vector_type(8)));

#define AS1 __attribute__((address_space(1)))
#define AS3 __attribute__((address_space(3)))

// ---------------------------------------------------------------------------
// r20 (= r19 with the cvt fix): eliminate the conv_x pass. gemm14 DMAs fp32 X
// straight to LDS (global_load_lds; NOT r2-4's reg-staging) and converts at
// fragment read via scalar (f16) casts (compiler fuses to v_cvt_pkrtz; m240:
// don't hand-write the builtin). A: BK=32 fp32 quarters [64][32] (same
// 128B-stride 8-XOR layout as proven -> 0 conflicts), triple-buffered
// (96 KiB). B: f16 K=64 tiles verbatim gemm12, double-buffered (64 KiB).
// Total 160 KiB. Gates: even tile VMW(8), odd VMW(4) (trace: drains exactly
// the next tile's operands, keeps A(KT+2) in flight); VMW(0) only tile 30.
// SYNC INVARIANT (r9): VMW(n) -> s_barrier before cross-wave LDS read.
// Workspace: Wl = LINEAR W_eff (2 MiB) @0; Xs @2MiB+4096 (fallback only).
// ---------------------------------------------------------------------------

__device__ __forceinline__ int compute_mode(const unsigned short* __restrict__ w,
                                            float* smax, int* semax) {
  int t = threadIdx.x;
  const float* wf = (const float*)w;
  float m32 = fmaxf(fabsf(wf[t]), fabsf(wf[t + 256]));
  int e8 = 0;
#pragma unroll
  for (int j = 0; j < 8; ++j) {
    unsigned short u = w[t * 8 + j];
    int e = (u >> 7) & 0xFF;
    e8 = e > e8 ? e : e8;
  }
  smax[t] = m32; semax[t] = e8;
  __syncthreads();
  for (int s = 128; s > 0; s >>= 1) {
    if (t < s) {
      smax[t] = fmaxf(smax[t], smax[t + s]);
      semax[t] = semax[t] > semax[t + s] ? semax[t] : semax[t + s];
    }
    __syncthreads();
  }
  int m;
  if (!(smax[0] > 1e-6f)) m = 2;        // native f16
  else if (semax[0] >= 140) m = 0;      // f32-upcast
  else m = 1;                           // bf16
  return m;
}

__device__ __forceinline__ float load_w(const void* base, size_t i, int mode) {
  if (mode == 0) return ((const float*)base)[i];
  if (mode == 1) {
    unsigned int u = (unsigned int)((const unsigned short*)base)[i] << 16;
    return __uint_as_float(u);
  }
  return (float)((const f16*)base)[i];
}

__global__ void prep_base(const void* __restrict__ base, f16* __restrict__ Wl) {
  __shared__ float smax[256];
  __shared__ int semax[256];
  int mode = compute_mode((const unsigned short*)base, smax, semax);
  int id = blockIdx.x * 256 + threadIdx.x;
  size_t off = (size_t)id * 8;
  f16x8 h;
  if (mode == 0) {
    const float* b = (const float*)base + off;
    float4 v0 = *reinterpret_cast<const float4*>(b);
    float4 v1 = *reinterpret_cast<const float4*>(b + 4);
    h = (f16x8){(f16)v0.x, (f16)v0.y, (f16)v0.z, (f16)v0.w,
                (f16)v1.x, (f16)v1.y, (f16)v1.z, (f16)v1.w};
  } else if (mode == 1) {
    ushort8 uv = *reinterpret_cast<const ushort8*>((const unsigned short*)base + off);
#pragma unroll
    for (int j = 0; j < 8; ++j)
      h[j] = (f16)__uint_as_float((unsigned int)uv[j] << 16);
  } else {
    h = *reinterpret_cast<const f16x8*>((const f16*)base + off);
  }
  *reinterpret_cast<f16x8*>(Wl + off) = h;
}

__global__ void prep_scatter(const void* __restrict__ base,
                             const void* __restrict__ vals,
                             const int* __restrict__ idx,
                             const float* __restrict__ alpha,
                             f16* __restrict__ Wl) {
  __shared__ float smax[256];
  __shared__ int semax[256];
  int mode = compute_mode((const unsigned short*)base, smax, semax);
  int i = blockIdx.x * 256 + threadIdx.x;
  if (i >= NNZ) return;
  int id = idx[i];
  float v = load_w(base, id, mode) + alpha[0] * load_w(vals, i, mode);
  Wl[id] = (f16)v;
}

// conv_x (fallback path only): linear cvt copy.
__global__ void __launch_bounds__(256) conv_x(const float* __restrict__ X,
                                              f16* __restrict__ Xs, int total) {
  int stride = gridDim.x * 256;
  for (int id = blockIdx.x * 256 + threadIdx.x; id < total; id += stride) {
    size_t off = (size_t)id * 8;
    const float* p = X + off;
    float4 v0 = *reinterpret_cast<const float4*>(p);
    float4 v1 = *reinterpret_cast<const float4*>(p + 4);
    f16x8 h = {(f16)v0.x, (f16)v0.y, (f16)v0.z, (f16)v0.w,
               (f16)v1.x, (f16)v1.y, (f16)v1.z, (f16)v1.w};
    *reinterpret_cast<f16x8*>(Xs + off) = h;
  }
}

#define SB0 __builtin_amdgcn_sched_barrier(0)
#define VMW(N) asm volatile("s_waitcnt vmcnt(" #N ")" ::: "memory")

// ---------------------------------------------------------------------------
// gemm14: 256x256, 512 thr (8 waves 2Mx4N), wave tile 128x64.
// A: fp32, BK=32, 32 K-tiles, triple-buffered [3][4 quarters][64][32]f32.
// B: f16, K=64 tiles (ktB = KT>>1), double-buffered [2][4 quarters][64][64].
// Tile KT: {ds_read A(+cvt) & B(S=KT&1); even: issue B(ktB+1); 32 MFMA;
//           KT<=29: issue A(KT+2); gate: VMW(8 even / 4 odd) -> s_barrier
//           -> SB0}. VMW(0) only at KT=30; no gate after KT=31.
// ---------------------------------------------------------------------------

#define ISSUE_A14(QI, KT1, AP)                                                 \
    __builtin_amdgcn_global_load_lds(                                          \
        (const AS1 void*)(X + rowOffA[QI] + (KT1) * 32 + swzcA),               \
        (AS3 void*)(&sAf[((AP) * 4 + (QI)) * 2048 + t * 4]), 16, 0, 0)

#define ISSUE_B14(QI, KTB1, BP)                                                \
    __builtin_amdgcn_global_load_lds(                                          \
        (const AS1 void*)(Wl + rowOffB[QI] + (KTB1) * 64 + swzc),              \
        (AS3 void*)(&sB[((BP) * 4 + (QI)) * 4096 + t * 8]), 16, 0, 0)

#define DSREAD_A14(AP) do {                                                    \
    _Pragma("unroll")                                                          \
    for (int qq_ = 0; qq_ < 2; ++qq_) {                                        \
      int qa_ = ((AP) * 4 + wm * 2 + qq_) * 2048;                              \
      _Pragma("unroll")                                                        \
      for (int mf_ = 0; mf_ < 4; ++mf_) {                                      \
        int r_ = mf_ * 16 + lr;                                                \
        f32x4 a0_ = *reinterpret_cast<const f32x4*>(                           \
            &sAf[qa_ + r_ * 32 + (((2 * lk) ^ (r_ & 7)) << 2)]);               \
        f32x4 a1_ = *reinterpret_cast<const f32x4*>(                           \
            &sAf[qa_ + r_ * 32 + (((2 * lk + 1) ^ (r_ & 7)) << 2)]);           \
        afr[qq_][mf_] = (f16x8){(f16)a0_[0], (f16)a0_[1], (f16)a0_[2],         \
                                (f16)a0_[3], (f16)a1_[0], (f16)a1_[1],         \
                                (f16)a1_[2], (f16)a1_[3]};                     \
      }                                                                        \
    }                                                                          \
  } while (0)

#define DSREAD_B14(BP, S_) do {                                                \
    int qb_ = ((BP) * 4 + wn) * 4096;                                          \
    _Pragma("unroll")                                                          \
    for (int nf_ = 0; nf_ < 4; ++nf_) {                                        \
      int r_ = nf_ * 16 + lr;                                                  \
      int blk_ = ((S_) * 4 + lk) ^ (lr & 7);                                   \
      bfr[nf_] = *reinterpret_cast<const f16x8*>(&sB[qb_ + r_ * 64 + blk_ * 8]); \
    }                                                                          \
  } while (0)

#define MFMA32_14 do {                                                         \
    __builtin_amdgcn_s_setprio(1);                                             \
    _Pragma("unroll")                                                          \
    for (int qq_ = 0; qq_ < 2; ++qq_)                                          \
      _Pragma("unroll")                                                        \
      for (int mf_ = 0; mf_ < 4; ++mf_)                                        \
        _Pragma("unroll")                                                      \
        for (int nf_ = 0; nf_ < 4; ++nf_)                                      \
          acc[qq_ * 4 + mf_][nf_] = __builtin_amdgcn_mfma_f32_16x16x32_f16(    \
              afr[qq_][mf_], bfr[nf_], acc[qq_ * 4 + mf_][nf_], 0, 0, 0);      \
    __builtin_amdgcn_s_setprio(0);                                             \
  } while (0)

#define KTILE14(AP, BP, S_, KT, ISSB, ISSA, VMN, GATE) do {                    \
    DSREAD_A14(AP);                                                            \
    DSREAD_B14(BP, S_);                                                        \
    if (ISSB) {                                                                \
      ISSUE_B14(0, ((KT) >> 1) + 1, (((KT) >> 1) + 1) & 1);                    \
      ISSUE_B14(1, ((KT) >> 1) + 1, (((KT) >> 1) + 1) & 1);                    \
      ISSUE_B14(2, ((KT) >> 1) + 1, (((KT) >> 1) + 1) & 1);                    \
      ISSUE_B14(3, ((KT) >> 1) + 1, (((KT) >> 1) + 1) & 1); }                  \
    MFMA32_14;                                                                 \
    if (ISSA) {                                                                \
      ISSUE_A14(0, (KT) + 2, ((KT) + 2) % 3);                                  \
      ISSUE_A14(1, (KT) + 2, ((KT) + 2) % 3);                                  \
      ISSUE_A14(2, (KT) + 2, ((KT) + 2) % 3);                                  \
      ISSUE_A14(3, (KT) + 2, ((KT) + 2) % 3); }                                \
    if (GATE) {                                                                \
      VMW(VMN);                                                                \
      __builtin_amdgcn_s_barrier();  /* WAR(this) + RAW(next), r9 */           \
      SB0;                           /* hoist guard */                         \
    }                                                                          \
  } while (0)

__global__ void __launch_bounds__(512, 2) gemm14(const float* __restrict__ X,
                                                 const f16* __restrict__ Wl,
                                                 float* __restrict__ C) {
  extern __shared__ char lds[];
  float* sAf = (float*)lds;                    // 3 x 4 x 2048 f32 = 96 KiB
  f16* sB = (f16*)(lds + 98304);               // 2 x 4 x 4096 f16 = 64 KiB

  int bidx = blockIdx.x;
  int q = gridDim.x >> 3;
  int wg = (bidx & 7) * q + (bidx >> 3);
  int mt = wg >> 2, nt = wg & 3;

  int t = threadIdx.x;
  int lane = t & 63;
  int w = t >> 6;
  int wm = w >> 2;           // M half (128 rows) -> A quarters 2wm, 2wm+1
  int wn = w & 3;            // N quarter (64 cols) == B row-quarter
  int lr = lane & 15;
  int lk = lane >> 4;

  int rS = t >> 3;
  int swzc = (((t & 7) ^ (rS & 7)) << 3);      // f16 units (B)
  int swzcA = (((t & 7) ^ (rS & 7)) << 2);     // f32 units (A)
  size_t rowOffA[4], rowOffB[4];
#pragma unroll
  for (int qi = 0; qi < 4; ++qi) {
    rowOffA[qi] = (size_t)(mt * 256 + qi * 64 + rS) * IN_F;
    rowOffB[qi] = (size_t)(nt * 256 + qi * 64 + rS) * IN_F;
  }

  f16x8 afr[2][4], bfr[4];
  f32x4 acc[8][4];
#pragma unroll
  for (int i = 0; i < 8; ++i)
#pragma unroll
    for (int j = 0; j < 4; ++j)
      acc[i][j] = (f32x4){0.f, 0.f, 0.f, 0.f};

  // prologue: A(0)->buf0, B(0)->bufB0, A(1)->buf1; VMW(4) drains A0+B0,
  // keeps A(1) in flight; barrier (r9).
  ISSUE_A14(0, 0, 0); ISSUE_A14(1, 0, 0); ISSUE_A14(2, 0, 0); ISSUE_A14(3, 0, 0);
  ISSUE_B14(0, 0, 0); ISSUE_B14(1, 0, 0); ISSUE_B14(2, 0, 0); ISSUE_B14(3, 0, 0);
  ISSUE_A14(0, 1, 1); ISSUE_A14(1, 1, 1); ISSUE_A14(2, 1, 1); ISSUE_A14(3, 1, 1);
  VMW(4);
  __builtin_amdgcn_s_barrier();
  SB0;

  // KT: AP=KT%3, BP=(KT>>1)&1, S=KT&1; ISSB: even KT<=28; ISSA: KT<=29;
  // VMN: even 8 / odd 4; KT=30: VMW(0); KT=31: no gate.
  KTILE14(0, 0, 0,  0, true,  true,  8, true);
  KTILE14(1, 0, 1,  1, false, true,  4, true);
  KTILE14(2, 1, 0,  2, true,  true,  8, true);
  KTILE14(0, 1, 1,  3, false, true,  4, true);
  KTILE14(1, 0, 0,  4, true,  true,  8, true);
  KTILE14(2, 0, 1,  5, false, true,  4, true);
  KTILE14(0, 1, 0,  6, true,  true,  8, true);
  KTILE14(1, 1, 1,  7, false, true,  4, true);
  KTILE14(2, 0, 0,  8, true,  true,  8, true);
  KTILE14(0, 0, 1,  9, false, true,  4, true);
  KTILE14(1, 1, 0, 10, true,  true,  8, true);
  KTILE14(2, 1, 1, 11, false, true,  4, true);
  KTILE14(0, 0, 0, 12, true,  true,  8, true);
  KTILE14(1, 0, 1, 13, false, true,  4, true);
  KTILE14(2, 1, 0, 14, true,  true,  8, true);
  KTILE14(0, 1, 1, 15, false, true,  4, true);
  KTILE14(1, 0, 0, 16, true,  true,  8, true);
  KTILE14(2, 0, 1, 17, false, true,  4, true);
  KTILE14(0, 1, 0, 18, true,  true,  8, true);
  KTILE14(1, 1, 1, 19, false, true,  4, true);
  KTILE14(2, 0, 0, 20, true,  true,  8, true);
  KTILE14(0, 0, 1, 21, false, true,  4, true);
  KTILE14(1, 1, 0, 22, true,  true,  8, true);
  KTILE14(2, 1, 1, 23, false, true,  4, true);
  KTILE14(0, 0, 0, 24, true,  true,  8, true);
  KTILE14(1, 0, 1, 25, false, true,  4, true);
  KTILE14(2, 1, 0, 26, true,  true,  8, true);
  KTILE14(0, 1, 1, 27, false, true,  4, true);
  KTILE14(1, 0, 0, 28, true,  true,  8, true);
  KTILE14(2, 0, 1, 29, false, true,  4, true);
  KTILE14(0, 1, 0, 30, false, false, 0, true);
  KTILE14(1, 1, 1, 31, false, false, 0, false);

  // epilogue: D layout col = lane&15, row = (lane>>4)*4 + reg
  float* Cw = C + (size_t)(mt * 256 + wm * 128 + lk * 4) * OUT_F + nt * 256 + wn * 64 + lr;
#pragma unroll
  for (int m = 0; m < 8; ++m) {
    int rowo = (m >> 2) * 64 + (m & 3) * 16;
#pragma unroll
    for (int nf = 0; nf < 4; ++nf)
#pragma unroll
      for (int g = 0; g < 4; ++g)
        Cw[(size_t)(rowo + g) * OUT_F + nf * 16] = acc[m][nf][g];
  }
}

// ---------------------------------------------------------------------------
// gemm12 fallback (replay-proven r15-r18, ~71 us): f16 A via Xs + conv_x.
// ---------------------------------------------------------------------------

#define ISSUE_QA11(QI, KT1, AP)                                                \
    __builtin_amdgcn_global_load_lds(                                          \
        (const AS1 void*)(Xs + rowOffA[QI] + (KT1) * 64 + swzc),               \
        (AS3 void*)(&sA[((AP) * 4 + (QI)) * 4096 + t * 8]), 16, 0, 0)

#define ISSUE_QB11(QI, KT1, BP)                                                \
    __builtin_amdgcn_global_load_lds(                                          \
        (const AS1 void*)(Wl + rowOffB[QI] + (KT1) * 64 + swzc),               \
        (AS3 void*)(&sB[((BP) * 4 + (QI)) * 4096 + t * 8]), 16, 0, 0)

#define DSREAD11(AP, BP, S_) do {                                              \
    _Pragma("unroll")                                                          \
    for (int qq_ = 0; qq_ < 2; ++qq_) {                                        \
      int qa_ = ((AP) * 4 + wm * 2 + qq_) * 4096;                              \
      _Pragma("unroll")                                                        \
      for (int mf_ = 0; mf_ < 4; ++mf_) {                                      \
        int r_ = mf_ * 16 + lr;                                                \
        int blk_ = ((S_) * 4 + lk) ^ (lr & 7);                                 \
        afr[qq_][mf_] = *reinterpret_cast<const f16x8*>(&sA[qa_ + r_ * 64 + blk_ * 8]); \
      }                                                                        \
    }                                                                          \
    int qb_ = ((BP) * 4 + wn) * 4096;                                          \
    _Pragma("unroll")                                                          \
    for (int nf_ = 0; nf_ < 4; ++nf_) {                                        \
      int r_ = nf_ * 16 + lr;                                                  \
      int blk_ = ((S_) * 4 + lk) ^ (lr & 7);                                   \
      bfr[nf_] = *reinterpret_cast<const f16x8*>(&sB[qb_ + r_ * 64 + blk_ * 8]); \
    }                                                                          \
  } while (0)

#define KTILE12(AP, BP, KT, ISSB, ISSA, VMN, LASTBAR) do {                     \
    DSREAD11(AP, BP, 0);                                                       \
    if (ISSB) {                                                                \
      ISSUE_QB11(0, (KT) + 1, ((KT) + 1) & 1); ISSUE_QB11(1, (KT) + 1, ((KT) + 1) & 1); \
      ISSUE_QB11(2, (KT) + 1, ((KT) + 1) & 1); ISSUE_QB11(3, (KT) + 1, ((KT) + 1) & 1); } \
    MFMA32_14;                                                                 \
    DSREAD11(AP, BP, 1);                                                       \
    if (ISSA) {                                                                \
      ISSUE_QA11(0, (KT) + 2, ((KT) + 2) % 3); ISSUE_QA11(1, (KT) + 2, ((KT) + 2) % 3); \
      ISSUE_QA11(2, (KT) + 2, ((KT) + 2) % 3); ISSUE_QA11(3, (KT) + 2, ((KT) + 2) % 3); } \
    MFMA32_14;                                                                 \
    if (LASTBAR) {                                                             \
      VMW(VMN);                                                                \
      __builtin_amdgcn_s_barrier();                                            \
      SB0;                                                                     \
    }                                                                          \
  } while (0)

__global__ void __launch_bounds__(512, 2) gemm12(const f16* __restrict__ Xs,
                                                 const f16* __restrict__ Wl,
                                                 float* __restrict__ C) {
  extern __shared__ char lds[];
  f16* sA = (f16*)lds;
  f16* sB = (f16*)(lds + 98304);

  int bidx = blockIdx.x;
  int q = gridDim.x >> 3;
  int wg = (bidx & 7) * q + (bidx >> 3);
  int mt = wg >> 2, nt = wg & 3;

  int t = threadIdx.x;
  int lane = t & 63;
  int w = t >> 6;
  int wm = w >> 2;
  int wn = w & 3;
  int lr = lane & 15;
  int lk = lane >> 4;

  int rS = t >> 3;
  int swzc = (((t & 7) ^ (rS & 7)) << 3);
  size_t rowOffA[4], rowOffB[4];
#pragma unroll
  for (int qi = 0; qi < 4; ++qi) {
    rowOffA[qi] = (size_t)(mt * 256 + qi * 64 + rS) * IN_F;
    rowOffB[qi] = (size_t)(nt * 256 + qi * 64 + rS) * IN_F;
  }

  f16x8 afr[2][4], bfr[4];
  f32x4 acc[8][4];
#pragma unroll
  for (int i = 0; i < 8; ++i)
#pragma unroll
    for (int j = 0; j < 4; ++j)
      acc[i][j] = (f32x4){0.f, 0.f, 0.f, 0.f};

  ISSUE_QA11(0, 0, 0); ISSUE_QA11(1, 0, 0); ISSUE_QA11(2, 0, 0); ISSUE_QA11(3, 0, 0);
  ISSUE_QB11(0, 0, 0); ISSUE_QB11(1, 0, 0); ISSUE_QB11(2, 0, 0); ISSUE_QB11(3, 0, 0);
  ISSUE_QA11(0, 1, 1); ISSUE_QA11(1, 1, 1); ISSUE_QA11(2, 1, 1); ISSUE_QA11(3, 1, 1);
  VMW(4);
  __builtin_amdgcn_s_barrier();
  SB0;

  KTILE12(0, 0,  0, true,  true,  4, true);
  KTILE12(1, 1,  1, true,  true,  4, true);
  KTILE12(2, 0,  2, true,  true,  4, true);
  KTILE12(0, 1,  3, true,  true,  4, true);
  KTILE12(1, 0,  4, true,  true,  4, true);
  KTILE12(2, 1,  5, true,  true,  4, true);
  KTILE12(0, 0,  6, true,  true,  4, true);
  KTILE12(1, 1,  7, true,  true,  4, true);
  KTILE12(2, 0,  8, true,  true,  4, true);
  KTILE12(0, 1,  9, true,  true,  4, true);
  KTILE12(1, 0, 10, true,  true,  4, true);
  KTILE12(2, 1, 11, true,  true,  4, true);
  KTILE12(0, 0, 12, true,  true,  4, true);
  KTILE12(1, 1, 13, true,  true,  4, true);
  KTILE12(2, 0, 14, true,  false, 0, true);
  KTILE12(0, 1, 15, false, false, 0, false);

  float* Cw = C + (size_t)(mt * 256 + wm * 128 + lk * 4) * OUT_F + nt * 256 + wn * 64 + lr;
#pragma unroll
  for (int m = 0; m < 8; ++m) {
    int rowo = (m >> 2) * 64 + (m & 3) * 16;
#pragma unroll
    for (int nf = 0; nf < 4; ++nf)
#pragma unroll
      for (int g = 0; g < 4; ++g)
        Cw[(size_t)(rowo + g) * OUT_F + nf * 16] = acc[m][nf][g];
  }
}

extern "C" void kernel_launch(void* const* d_in, const int* in_sizes, int n_in,
                              void* d_out, int out_size, void* d_ws, size_t ws_size,
                              hipStream_t stream) {
  const float* X = (const float*)d_in[0];
  const void* base = d_in[1];
  const void* vals = d_in[2];
  const int* idx = (const int*)d_in[3];
  const float* alpha = (const float*)d_in[4];
  float* out = (float*)d_out;
  f16* Wl = (f16*)d_ws;                                   // linear W_eff
  f16* Xs = (f16*)((char*)d_ws + 2 * 1024 * 1024 + 4096); // fallback only

  int M = in_sizes[0] / IN_F;              // 32768
  int total = (M * IN_F) / 8;

  prep_base<<<dim3(512), dim3(256), 0, stream>>>(base, Wl);
  prep_scatter<<<dim3(64), dim3(256), 0, stream>>>(base, vals, idx, alpha, Wl);

  hipError_t e = hipFuncSetAttribute(reinterpret_cast<const void*>(&gemm14),
                                     hipFuncAttributeMaxDynamicSharedMemorySize, 163840);
  if (e == hipSuccess) {
    gemm14<<<dim3((M / 256) * 4), dim3(512), 163840, stream>>>(X, Wl, out);
  } else {
    (void)hipFuncSetAttribute(reinterpret_cast<const void*>(&gemm12),
                              hipFuncAttributeMaxDynamicSharedMemorySize, 163840);
    conv_x<<<dim3(2048), dim3(256), 0, stream>>>(X, Xs, total);
    gemm12<<<dim3((M / 256) * 4), dim3(512), 163840, stream>>>(Xs, Wl, out);
  }
}

// Round 21
// 104.916 us; speedup vs baseline: 1.1519x; 1.0027x over previous
//
#include <hip/hip_runtime.h>

#define IN_F 1024
#define OUT_F 1024
#define NNZ 16384

typedef _Float16 f16;
typedef _Float16 f16x8 __attribute__((ext_vector_type(8)));
typedef float f32x4 __attribute__((ext_vector_type(4)));
typedef unsigned short ushort8 __attribute__((ext_vector_type(8)));

#define AS1 __attribute__((address_space(1)))
#define AS3 __attribute__((address_space(3)))

// ---------------------------------------------------------------------------
// r21 (= r20 + A-read de-pairing): gemm14 DMAs fp32 X straight to LDS and
// converts at fragment read. r20 measured SQ_LDS_BANK_CONFLICT = 2^23 exactly
// (64 cyc/wave-tile); static bank math says the pattern matches the proven
// 0-conflict f16 layout, so the suspect is cross-instruction overlap of the
// paired reads (blk, blk^1) issued back-to-back. This round separates the
// two streams: per quarter, read all blk0s, then all blk1s, then pack.
// Everything else (schedule, gates, layouts) is r20 verbatim (replay-proven).
// SYNC INVARIANT (r9): VMW(n) -> s_barrier before cross-wave LDS read.
// Workspace: Wl = LINEAR W_eff (2 MiB) @0; Xs @2MiB+4096 (fallback only).
// ---------------------------------------------------------------------------

__device__ __forceinline__ int compute_mode(const unsigned short* __restrict__ w,
                                            float* smax, int* semax) {
  int t = threadIdx.x;
  const float* wf = (const float*)w;
  float m32 = fmaxf(fabsf(wf[t]), fabsf(wf[t + 256]));
  int e8 = 0;
#pragma unroll
  for (int j = 0; j < 8; ++j) {
    unsigned short u = w[t * 8 + j];
    int e = (u >> 7) & 0xFF;
    e8 = e > e8 ? e : e8;
  }
  smax[t] = m32; semax[t] = e8;
  __syncthreads();
  for (int s = 128; s > 0; s >>= 1) {
    if (t < s) {
      smax[t] = fmaxf(smax[t], smax[t + s]);
      semax[t] = semax[t] > semax[t + s] ? semax[t] : semax[t + s];
    }
    __syncthreads();
  }
  int m;
  if (!(smax[0] > 1e-6f)) m = 2;        // native f16
  else if (semax[0] >= 140) m = 0;      // f32-upcast
  else m = 1;                           // bf16
  return m;
}

__device__ __forceinline__ float load_w(const void* base, size_t i, int mode) {
  if (mode == 0) return ((const float*)base)[i];
  if (mode == 1) {
    unsigned int u = (unsigned int)((const unsigned short*)base)[i] << 16;
    return __uint_as_float(u);
  }
  return (float)((const f16*)base)[i];
}

__global__ void prep_base(const void* __restrict__ base, f16* __restrict__ Wl) {
  __shared__ float smax[256];
  __shared__ int semax[256];
  int mode = compute_mode((const unsigned short*)base, smax, semax);
  int id = blockIdx.x * 256 + threadIdx.x;
  size_t off = (size_t)id * 8;
  f16x8 h;
  if (mode == 0) {
    const float* b = (const float*)base + off;
    float4 v0 = *reinterpret_cast<const float4*>(b);
    float4 v1 = *reinterpret_cast<const float4*>(b + 4);
    h = (f16x8){(f16)v0.x, (f16)v0.y, (f16)v0.z, (f16)v0.w,
                (f16)v1.x, (f16)v1.y, (f16)v1.z, (f16)v1.w};
  } else if (mode == 1) {
    ushort8 uv = *reinterpret_cast<const ushort8*>((const unsigned short*)base + off);
#pragma unroll
    for (int j = 0; j < 8; ++j)
      h[j] = (f16)__uint_as_float((unsigned int)uv[j] << 16);
  } else {
    h = *reinterpret_cast<const f16x8*>((const f16*)base + off);
  }
  *reinterpret_cast<f16x8*>(Wl + off) = h;
}

__global__ void prep_scatter(const void* __restrict__ base,
                             const void* __restrict__ vals,
                             const int* __restrict__ idx,
                             const float* __restrict__ alpha,
                             f16* __restrict__ Wl) {
  __shared__ float smax[256];
  __shared__ int semax[256];
  int mode = compute_mode((const unsigned short*)base, smax, semax);
  int i = blockIdx.x * 256 + threadIdx.x;
  if (i >= NNZ) return;
  int id = idx[i];
  float v = load_w(base, id, mode) + alpha[0] * load_w(vals, i, mode);
  Wl[id] = (f16)v;
}

// conv_x (fallback path only): linear cvt copy.
__global__ void __launch_bounds__(256) conv_x(const float* __restrict__ X,
                                              f16* __restrict__ Xs, int total) {
  int stride = gridDim.x * 256;
  for (int id = blockIdx.x * 256 + threadIdx.x; id < total; id += stride) {
    size_t off = (size_t)id * 8;
    const float* p = X + off;
    float4 v0 = *reinterpret_cast<const float4*>(p);
    float4 v1 = *reinterpret_cast<const float4*>(p + 4);
    f16x8 h = {(f16)v0.x, (f16)v0.y, (f16)v0.z, (f16)v0.w,
               (f16)v1.x, (f16)v1.y, (f16)v1.z, (f16)v1.w};
    *reinterpret_cast<f16x8*>(Xs + off) = h;
  }
}

#define SB0 __builtin_amdgcn_sched_barrier(0)
#define VMW(N) asm volatile("s_waitcnt vmcnt(" #N ")" ::: "memory")

// ---------------------------------------------------------------------------
// gemm14: 256x256, 512 thr (8 waves 2Mx4N), wave tile 128x64.
// A: fp32, BK=32, 32 K-tiles, triple-buffered [3][4 quarters][64][32]f32.
// B: f16, K=64 tiles (ktB = KT>>1), double-buffered [2][4 quarters][64][64].
// Tile KT: {ds_read A (de-paired, +cvt) & B(S=KT&1); even: issue B(ktB+1);
//           32 MFMA; KT<=29: issue A(KT+2); gate: VMW(8 even / 4 odd) ->
//           s_barrier -> SB0}. VMW(0) only at KT=30; no gate after KT=31.
// ---------------------------------------------------------------------------

#define ISSUE_A14(QI, KT1, AP)                                                 \
    __builtin_amdgcn_global_load_lds(                                          \
        (const AS1 void*)(X + rowOffA[QI] + (KT1) * 32 + swzcA),               \
        (AS3 void*)(&sAf[((AP) * 4 + (QI)) * 2048 + t * 4]), 16, 0, 0)

#define ISSUE_B14(QI, KTB1, BP)                                                \
    __builtin_amdgcn_global_load_lds(                                          \
        (const AS1 void*)(Wl + rowOffB[QI] + (KTB1) * 64 + swzc),              \
        (AS3 void*)(&sB[((BP) * 4 + (QI)) * 4096 + t * 8]), 16, 0, 0)

// De-paired A fragment read: per quarter, all blk0 reads, then all blk1
// reads, then pack (breaks the blk/blk^1 instruction adjacency of r20).
#define DSREAD_A14(AP) do {                                                    \
    _Pragma("unroll")                                                          \
    for (int qq_ = 0; qq_ < 2; ++qq_) {                                        \
      int qa_ = ((AP) * 4 + wm * 2 + qq_) * 2048;                              \
      f32x4 t0_[4], t1_[4];                                                    \
      _Pragma("unroll")                                                        \
      for (int mf_ = 0; mf_ < 4; ++mf_) {                                      \
        int r_ = mf_ * 16 + lr;                                                \
        t0_[mf_] = *reinterpret_cast<const f32x4*>(                            \
            &sAf[qa_ + r_ * 32 + (((2 * lk) ^ (r_ & 7)) << 2)]);               \
      }                                                                        \
      _Pragma("unroll")                                                        \
      for (int mf_ = 0; mf_ < 4; ++mf_) {                                      \
        int r_ = mf_ * 16 + lr;                                                \
        t1_[mf_] = *reinterpret_cast<const f32x4*>(                            \
            &sAf[qa_ + r_ * 32 + (((2 * lk + 1) ^ (r_ & 7)) << 2)]);           \
      }                                                                        \
      _Pragma("unroll")                                                        \
      for (int mf_ = 0; mf_ < 4; ++mf_)                                        \
        afr[qq_][mf_] = (f16x8){(f16)t0_[mf_][0], (f16)t0_[mf_][1],            \
                                (f16)t0_[mf_][2], (f16)t0_[mf_][3],            \
                                (f16)t1_[mf_][0], (f16)t1_[mf_][1],            \
                                (f16)t1_[mf_][2], (f16)t1_[mf_][3]};           \
    }                                                                          \
  } while (0)

#define DSREAD_B14(BP, S_) do {                                                \
    int qb_ = ((BP) * 4 + wn) * 4096;                                          \
    _Pragma("unroll")                                                          \
    for (int nf_ = 0; nf_ < 4; ++nf_) {                                        \
      int r_ = nf_ * 16 + lr;                                                  \
      int blk_ = ((S_) * 4 + lk) ^ (lr & 7);                                   \
      bfr[nf_] = *reinterpret_cast<const f16x8*>(&sB[qb_ + r_ * 64 + blk_ * 8]); \
    }                                                                          \
  } while (0)

#define MFMA32_14 do {                                                         \
    __builtin_amdgcn_s_setprio(1);                                             \
    _Pragma("unroll")                                                          \
    for (int qq_ = 0; qq_ < 2; ++qq_)                                          \
      _Pragma("unroll")                                                        \
      for (int mf_ = 0; mf_ < 4; ++mf_)                                        \
        _Pragma("unroll")                                                      \
        for (int nf_ = 0; nf_ < 4; ++nf_)                                      \
          acc[qq_ * 4 + mf_][nf_] = __builtin_amdgcn_mfma_f32_16x16x32_f16(    \
              afr[qq_][mf_], bfr[nf_], acc[qq_ * 4 + mf_][nf_], 0, 0, 0);      \
    __builtin_amdgcn_s_setprio(0);                                             \
  } while (0)

#define KTILE14(AP, BP, S_, KT, ISSB, ISSA, VMN, GATE) do {                    \
    DSREAD_A14(AP);                                                            \
    DSREAD_B14(BP, S_);                                                        \
    if (ISSB) {                                                                \
      ISSUE_B14(0, ((KT) >> 1) + 1, (((KT) >> 1) + 1) & 1);                    \
      ISSUE_B14(1, ((KT) >> 1) + 1, (((KT) >> 1) + 1) & 1);                    \
      ISSUE_B14(2, ((KT) >> 1) + 1, (((KT) >> 1) + 1) & 1);                    \
      ISSUE_B14(3, ((KT) >> 1) + 1, (((KT) >> 1) + 1) & 1); }                  \
    MFMA32_14;                                                                 \
    if (ISSA) {                                                                \
      ISSUE_A14(0, (KT) + 2, ((KT) + 2) % 3);                                  \
      ISSUE_A14(1, (KT) + 2, ((KT) + 2) % 3);                                  \
      ISSUE_A14(2, (KT) + 2, ((KT) + 2) % 3);                                  \
      ISSUE_A14(3, (KT) + 2, ((KT) + 2) % 3); }                                \
    if (GATE) {                                                                \
      VMW(VMN);                                                                \
      __builtin_amdgcn_s_barrier();  /* WAR(this) + RAW(next), r9 */           \
      SB0;                           /* hoist guard */                         \
    }                                                                          \
  } while (0)

__global__ void __launch_bounds__(512, 2) gemm14(const float* __restrict__ X,
                                                 const f16* __restrict__ Wl,
                                                 float* __restrict__ C) {
  extern __shared__ char lds[];
  float* sAf = (float*)lds;                    // 3 x 4 x 2048 f32 = 96 KiB
  f16* sB = (f16*)(lds + 98304);               // 2 x 4 x 4096 f16 = 64 KiB

  int bidx = blockIdx.x;
  int q = gridDim.x >> 3;
  int wg = (bidx & 7) * q + (bidx >> 3);
  int mt = wg >> 2, nt = wg & 3;

  int t = threadIdx.x;
  int lane = t & 63;
  int w = t >> 6;
  int wm = w >> 2;           // M half (128 rows) -> A quarters 2wm, 2wm+1
  int wn = w & 3;            // N quarter (64 cols) == B row-quarter
  int lr = lane & 15;
  int lk = lane >> 4;

  int rS = t >> 3;
  int swzc = (((t & 7) ^ (rS & 7)) << 3);      // f16 units (B)
  int swzcA = (((t & 7) ^ (rS & 7)) << 2);     // f32 units (A)
  size_t rowOffA[4], rowOffB[4];
#pragma unroll
  for (int qi = 0; qi < 4; ++qi) {
    rowOffA[qi] = (size_t)(mt * 256 + qi * 64 + rS) * IN_F;
    rowOffB[qi] = (size_t)(nt * 256 + qi * 64 + rS) * IN_F;
  }

  f16x8 afr[2][4], bfr[4];
  f32x4 acc[8][4];
#pragma unroll
  for (int i = 0; i < 8; ++i)
#pragma unroll
    for (int j = 0; j < 4; ++j)
      acc[i][j] = (f32x4){0.f, 0.f, 0.f, 0.f};

  // prologue: A(0)->buf0, B(0)->bufB0, A(1)->buf1; VMW(4) drains A0+B0,
  // keeps A(1) in flight; barrier (r9).
  ISSUE_A14(0, 0, 0); ISSUE_A14(1, 0, 0); ISSUE_A14(2, 0, 0); ISSUE_A14(3, 0, 0);
  ISSUE_B14(0, 0, 0); ISSUE_B14(1, 0, 0); ISSUE_B14(2, 0, 0); ISSUE_B14(3, 0, 0);
  ISSUE_A14(0, 1, 1); ISSUE_A14(1, 1, 1); ISSUE_A14(2, 1, 1); ISSUE_A14(3, 1, 1);
  VMW(4);
  __builtin_amdgcn_s_barrier();
  SB0;

  // KT: AP=KT%3, BP=(KT>>1)&1, S=KT&1; ISSB: even KT<=28; ISSA: KT<=29;
  // VMN: even 8 / odd 4; KT=30: VMW(0); KT=31: no gate.
  KTILE14(0, 0, 0,  0, true,  true,  8, true);
  KTILE14(1, 0, 1,  1, false, true,  4, true);
  KTILE14(2, 1, 0,  2, true,  true,  8, true);
  KTILE14(0, 1, 1,  3, false, true,  4, true);
  KTILE14(1, 0, 0,  4, true,  true,  8, true);
  KTILE14(2, 0, 1,  5, false, true,  4, true);
  KTILE14(0, 1, 0,  6, true,  true,  8, true);
  KTILE14(1, 1, 1,  7, false, true,  4, true);
  KTILE14(2, 0, 0,  8, true,  true,  8, true);
  KTILE14(0, 0, 1,  9, false, true,  4, true);
  KTILE14(1, 1, 0, 10, true,  true,  8, true);
  KTILE14(2, 1, 1, 11, false, true,  4, true);
  KTILE14(0, 0, 0, 12, true,  true,  8, true);
  KTILE14(1, 0, 1, 13, false, true,  4, true);
  KTILE14(2, 1, 0, 14, true,  true,  8, true);
  KTILE14(0, 1, 1, 15, false, true,  4, true);
  KTILE14(1, 0, 0, 16, true,  true,  8, true);
  KTILE14(2, 0, 1, 17, false, true,  4, true);
  KTILE14(0, 1, 0, 18, true,  true,  8, true);
  KTILE14(1, 1, 1, 19, false, true,  4, true);
  KTILE14(2, 0, 0, 20, true,  true,  8, true);
  KTILE14(0, 0, 1, 21, false, true,  4, true);
  KTILE14(1, 1, 0, 22, true,  true,  8, true);
  KTILE14(2, 1, 1, 23, false, true,  4, true);
  KTILE14(0, 0, 0, 24, true,  true,  8, true);
  KTILE14(1, 0, 1, 25, false, true,  4, true);
  KTILE14(2, 1, 0, 26, true,  true,  8, true);
  KTILE14(0, 1, 1, 27, false, true,  4, true);
  KTILE14(1, 0, 0, 28, true,  true,  8, true);
  KTILE14(2, 0, 1, 29, false, true,  4, true);
  KTILE14(0, 1, 0, 30, false, false, 0, true);
  KTILE14(1, 1, 1, 31, false, false, 0, false);

  // epilogue: D layout col = lane&15, row = (lane>>4)*4 + reg
  float* Cw = C + (size_t)(mt * 256 + wm * 128 + lk * 4) * OUT_F + nt * 256 + wn * 64 + lr;
#pragma unroll
  for (int m = 0; m < 8; ++m) {
    int rowo = (m >> 2) * 64 + (m & 3) * 16;
#pragma unroll
    for (int nf = 0; nf < 4; ++nf)
#pragma unroll
      for (int g = 0; g < 4; ++g)
        Cw[(size_t)(rowo + g) * OUT_F + nf * 16] = acc[m][nf][g];
  }
}

// ---------------------------------------------------------------------------
// gemm12 fallback (replay-proven r15-r18, ~71 us): f16 A via Xs + conv_x.
// ---------------------------------------------------------------------------

#define ISSUE_QA11(QI, KT1, AP)                                                \
    __builtin_amdgcn_global_load_lds(                                          \
        (const AS1 void*)(Xs + rowOffA[QI] + (KT1) * 64 + swzc),               \
        (AS3 void*)(&sA[((AP) * 4 + (QI)) * 4096 + t * 8]), 16, 0, 0)

#define ISSUE_QB11(QI, KT1, BP)                                                \
    __builtin_amdgcn_global_load_lds(                                          \
        (const AS1 void*)(Wl + rowOffB[QI] + (KT1) * 64 + swzc),               \
        (AS3 void*)(&sB[((BP) * 4 + (QI)) * 4096 + t * 8]), 16, 0, 0)

#define DSREAD11(AP, BP, S_) do {                                              \
    _Pragma("unroll")                                                          \
    for (int qq_ = 0; qq_ < 2; ++qq_) {                                        \
      int qa_ = ((AP) * 4 + wm * 2 + qq_) * 4096;                              \
      _Pragma("unroll")                                                        \
      for (int mf_ = 0; mf_ < 4; ++mf_) {                                      \
        int r_ = mf_ * 16 + lr;                                                \
        int blk_ = ((S_) * 4 + lk) ^ (lr & 7);                                 \
        afr[qq_][mf_] = *reinterpret_cast<const f16x8*>(&sA[qa_ + r_ * 64 + blk_ * 8]); \
      }                                                                        \
    }                                                                          \
    int qb_ = ((BP) * 4 + wn) * 4096;                                          \
    _Pragma("unroll")                                                          \
    for (int nf_ = 0; nf_ < 4; ++nf_) {                                        \
      int r_ = nf_ * 16 + lr;                                                  \
      int blk_ = ((S_) * 4 + lk) ^ (lr & 7);                                   \
      bfr[nf_] = *reinterpret_cast<const f16x8*>(&sB[qb_ + r_ * 64 + blk_ * 8]); \
    }                                                                          \
  } while (0)

#define KTILE12(AP, BP, KT, ISSB, ISSA, VMN, LASTBAR) do {                     \
    DSREAD11(AP, BP, 0);                                                       \
    if (ISSB) {                                                                \
      ISSUE_QB11(0, (KT) + 1, ((KT) + 1) & 1); ISSUE_QB11(1, (KT) + 1, ((KT) + 1) & 1); \
      ISSUE_QB11(2, (KT) + 1, ((KT) + 1) & 1); ISSUE_QB11(3, (KT) + 1, ((KT) + 1) & 1); } \
    MFMA32_14;                                                                 \
    DSREAD11(AP, BP, 1);                                                       \
    if (ISSA) {                                                                \
      ISSUE_QA11(0, (KT) + 2, ((KT) + 2) % 3); ISSUE_QA11(1, (KT) + 2, ((KT) + 2) % 3); \
      ISSUE_QA11(2, (KT) + 2, ((KT) + 2) % 3); ISSUE_QA11(3, (KT) + 2, ((KT) + 2) % 3); } \
    MFMA32_14;                                                                 \
    if (LASTBAR) {                                                             \
      VMW(VMN);                                                                \
      __builtin_amdgcn_s_barrier();                                            \
      SB0;                                                                     \
    }                                                                          \
  } while (0)

__global__ void __launch_bounds__(512, 2) gemm12(const f16* __restrict__ Xs,
                                                 const f16* __restrict__ Wl,
                                                 float* __restrict__ C) {
  extern __shared__ char lds[];
  f16* sA = (f16*)lds;
  f16* sB = (f16*)(lds + 98304);

  int bidx = blockIdx.x;
  int q = gridDim.x >> 3;
  int wg = (bidx & 7) * q + (bidx >> 3);
  int mt = wg >> 2, nt = wg & 3;

  int t = threadIdx.x;
  int lane = t & 63;
  int w = t >> 6;
  int wm = w >> 2;
  int wn = w & 3;
  int lr = lane & 15;
  int lk = lane >> 4;

  int rS = t >> 3;
  int swzc = (((t & 7) ^ (rS & 7)) << 3);
  size_t rowOffA[4], rowOffB[4];
#pragma unroll
  for (int qi = 0; qi < 4; ++qi) {
    rowOffA[qi] = (size_t)(mt * 256 + qi * 64 + rS) * IN_F;
    rowOffB[qi] = (size_t)(nt * 256 + qi * 64 + rS) * IN_F;
  }

  f16x8 afr[2][4], bfr[4];
  f32x4 acc[8][4];
#pragma unroll
  for (int i = 0; i < 8; ++i)
#pragma unroll
    for (int j = 0; j < 4; ++j)
      acc[i][j] = (f32x4){0.f, 0.f, 0.f, 0.f};

  ISSUE_QA11(0, 0, 0); ISSUE_QA11(1, 0, 0); ISSUE_QA11(2, 0, 0); ISSUE_QA11(3, 0, 0);
  ISSUE_QB11(0, 0, 0); ISSUE_QB11(1, 0, 0); ISSUE_QB11(2, 0, 0); ISSUE_QB11(3, 0, 0);
  ISSUE_QA11(0, 1, 1); ISSUE_QA11(1, 1, 1); ISSUE_QA11(2, 1, 1); ISSUE_QA11(3, 1, 1);
  VMW(4);
  __builtin_amdgcn_s_barrier();
  SB0;

  KTILE12(0, 0,  0, true,  true,  4, true);
  KTILE12(1, 1,  1, true,  true,  4, true);
  KTILE12(2, 0,  2, true,  true,  4, true);
  KTILE12(0, 1,  3, true,  true,  4, true);
  KTILE12(1, 0,  4, true,  true,  4, true);
  KTILE12(2, 1,  5, true,  true,  4, true);
  KTILE12(0, 0,  6, true,  true,  4, true);
  KTILE12(1, 1,  7, true,  true,  4, true);
  KTILE12(2, 0,  8, true,  true,  4, true);
  KTILE12(0, 1,  9, true,  true,  4, true);
  KTILE12(1, 0, 10, true,  true,  4, true);
  KTILE12(2, 1, 11, true,  true,  4, true);
  KTILE12(0, 0, 12, true,  true,  4, true);
  KTILE12(1, 1, 13, true,  true,  4, true);
  KTILE12(2, 0, 14, true,  false, 0, true);
  KTILE12(0, 1, 15, false, false, 0, false);

  float* Cw = C + (size_t)(mt * 256 + wm * 128 + lk * 4) * OUT_F + nt * 256 + wn * 64 + lr;
#pragma unroll
  for (int m = 0; m < 8; ++m) {
    int rowo = (m >> 2) * 64 + (m & 3) * 16;
#pragma unroll
    for (int nf = 0; nf < 4; ++nf)
#pragma unroll
      for (int g = 0; g < 4; ++g)
        Cw[(size_t)(rowo + g) * OUT_F + nf * 16] = acc[m][nf][g];
  }
}

extern "C" void kernel_launch(void* const* d_in, const int* in_sizes, int n_in,
                              void* d_out, int out_size, void* d_ws, size_t ws_size,
                              hipStream_t stream) {
  const float* X = (const float*)d_in[0];
  const void* base = d_in[1];
  const void* vals = d_in[2];
  const int* idx = (const int*)d_in[3];
  const float* alpha = (const float*)d_in[4];
  float* out = (float*)d_out;
  f16* Wl = (f16*)d_ws;                                   // linear W_eff
  f16* Xs = (f16*)((char*)d_ws + 2 * 1024 * 1024 + 4096); // fallback only

  int M = in_sizes[0] / IN_F;              // 32768
  int total = (M * IN_F) / 8;

  prep_base<<<dim3(512), dim3(256), 0, stream>>>(base, Wl);
  prep_scatter<<<dim3(64), dim3(256), 0, stream>>>(base, vals, idx, alpha, Wl);

  hipError_t e = hipFuncSetAttribute(reinterpret_cast<const void*>(&gemm14),
                                     hipFuncAttributeMaxDynamicSharedMemorySize, 163840);
  if (e == hipSuccess) {
    gemm14<<<dim3((M / 256) * 4), dim3(512), 163840, stream>>>(X, Wl, out);
  } else {
    (void)hipFuncSetAttribute(reinterpret_cast<const void*>(&gemm12),
                              hipFuncAttributeMaxDynamicSharedMemorySize, 163840);
    conv_x<<<dim3(2048), dim3(256), 0, stream>>>(X, Xs, total);
    gemm12<<<dim3((M / 256) * 4), dim3(512), 163840, stream>>>(Xs, Wl, out);
  }
}